// Round 7
// baseline (380.109 us; speedup 1.0000x reference)
//
#include <hip/hip_runtime.h>
#include <hip/hip_bf16.h>

// Problem constants
#define Bb 256
#define Tt 128
#define Nn 512
#define Hh 128
// 4H = 512

typedef __attribute__((ext_vector_type(4))) float floatx4;
typedef __attribute__((ext_vector_type(8))) short short8;

__device__ __forceinline__ unsigned short f2bf(float f) {
  unsigned u = __float_as_uint(f);
  u += 0x7fffu + ((u >> 16) & 1u);   // round-to-nearest-even
  return (unsigned short)(u >> 16);
}

// Fast activations: v_exp + v_rcp (~1ulp each) instead of IEEE div sequences.
__device__ __forceinline__ float sigmoid_fast(float x) {
  return __builtin_amdgcn_rcpf(1.f + __expf(-x));
}
__device__ __forceinline__ float tanh_fast(float x) {
  float e = __expf(2.f * x);                       // inf-safe
  return 1.f - 2.f * __builtin_amdgcn_rcpf(e + 1.f);
}

// Workgroup barrier that does NOT drain vmcnt: only LDS ops are waited.
// Global loads/stores issued before it stay in flight across the barrier.
__device__ __forceinline__ void lds_barrier() {
  asm volatile("s_waitcnt lgkmcnt(0)" ::: "memory");
  __builtin_amdgcn_s_barrier();
  asm volatile("" ::: "memory");
}

__device__ __forceinline__ void async_load16(const void* g, void* lds) {
  __builtin_amdgcn_global_load_lds(
      (const __attribute__((address_space(1))) unsigned int*)g,
      (__attribute__((address_space(3))) unsigned int*)lds, 16, 0, 0);
}

// ---------------------------------------------------------------------------
// Kernel 1: convert w_ih to bf16, precompute bias = b_ih + b_hh
// ---------------------------------------------------------------------------
__global__ void prep_kernel(const float* __restrict__ w_ih,
                            const float* __restrict__ b_ih,
                            const float* __restrict__ b_hh,
                            unsigned short* __restrict__ wb,
                            float* __restrict__ bias) {
  int i = blockIdx.x * 256 + threadIdx.x;
  if (i < 4 * Hh * Nn) wb[i] = f2bf(w_ih[i]);
  if (i < 4 * Hh) bias[i] = b_ih[i] + b_hh[i];
}

// ---------------------------------------------------------------------------
// Kernel 2 (fused): alpha[b,n] = softmax_n( sum_t X[b,t,n] * w_x[t] ), kept
// in LDS; then Xt = alpha * X (fp32 output 0) and xtb = bf16(Xt) in the same
// block. X[b] (256 KB) is read from HBM once; the scale pass re-reads it
// mostly through L2. Saves the alpha global round-trip + one HBM X pass.
// ---------------------------------------------------------------------------
__global__ __launch_bounds__(512) void alpha_scale_kernel(const float* __restrict__ X,
                                                          const float* __restrict__ attn_w,
                                                          float* __restrict__ Xt,
                                                          unsigned short* __restrict__ xtb) {
  int b = blockIdx.x;
  int tid = threadIdx.x;
  int c = tid & 127;        // float4 column index (n = 4c..4c+3)
  int tp = tid >> 7;        // 4-way t-split
  const float4* Xb4 = (const float4*)(X + (size_t)b * Tt * Nn);
  const float* wx = attn_w + 2 * Hh;

  float4 acc = {0.f, 0.f, 0.f, 0.f};
#pragma unroll 8
  for (int tt = 0; tt < 32; ++tt) {
    int t = tp * 32 + tt;
    float4 x = Xb4[(size_t)t * 128 + c];
    float w = wx[t];
    acc.x = fmaf(x.x, w, acc.x);
    acc.y = fmaf(x.y, w, acc.y);
    acc.z = fmaf(x.z, w, acc.z);
    acc.w = fmaf(x.w, w, acc.w);
  }

  __shared__ float4 s4[512];       // 8 KB
  __shared__ float sred[128];
  __shared__ __align__(16) float salpha[512];
  s4[tid] = acc;
  __syncthreads();

  float4 sc = {0.f, 0.f, 0.f, 0.f};
  if (tid < 128) {
    float4 a = s4[tid], b2 = s4[tid + 128], c2 = s4[tid + 256], d = s4[tid + 384];
    sc.x = a.x + b2.x + c2.x + d.x;
    sc.y = a.y + b2.y + c2.y + d.y;
    sc.z = a.z + b2.z + c2.z + d.z;
    sc.w = a.w + b2.w + c2.w + d.w;
    sred[tid] = fmaxf(fmaxf(sc.x, sc.y), fmaxf(sc.z, sc.w));
  }
  __syncthreads();
  for (int s = 64; s > 0; s >>= 1) {
    if (tid < s) sred[tid] = fmaxf(sred[tid], sred[tid + s]);
    __syncthreads();
  }
  float m = sred[0];
  __syncthreads();

  float4 e4 = {0.f, 0.f, 0.f, 0.f};
  if (tid < 128) {
    e4.x = __expf(sc.x - m);
    e4.y = __expf(sc.y - m);
    e4.z = __expf(sc.z - m);
    e4.w = __expf(sc.w - m);
    sred[tid] = e4.x + e4.y + e4.z + e4.w;
  }
  __syncthreads();
  for (int s = 64; s > 0; s >>= 1) {
    if (tid < s) sred[tid] += sred[tid + s];
    __syncthreads();
  }
  float inv = 1.f / sred[0];       // one precise division per block
  if (tid < 128) {
    float4 out;
    out.x = e4.x * inv; out.y = e4.y * inv; out.z = e4.z * inv; out.w = e4.w * inv;
    ((float4*)salpha)[tid] = out;
  }
  __syncthreads();

  // Scale pass: 16384 float4 per batch, 32 per thread.
  float4* Xt4 = (float4*)(Xt + (size_t)b * Tt * Nn);
  ushort4* xt4 = (ushort4*)(xtb + (size_t)b * Tt * Nn);
#pragma unroll 4
  for (int i = 0; i < 32; ++i) {
    int idx = i * 512 + tid;
    int n4 = idx & 127;            // float4-column
    float4 x = Xb4[idx];
    float4 a = *(const float4*)(&salpha[n4 * 4]);
    float4 y;
    y.x = x.x * a.x; y.y = x.y * a.y; y.z = x.z * a.z; y.w = x.w * a.w;
    Xt4[idx] = y;
    ushort4 u;
    u.x = f2bf(y.x); u.y = f2bf(y.y); u.z = f2bf(y.z); u.w = f2bf(y.w);
    xt4[idx] = u;
  }
}

// ---------------------------------------------------------------------------
// Kernel 4: G[m, j] = sum_k xtb[m,k] * w_ih[j,k] + bias[j]   (bf16 MFMA)
// M = B*T = 32768, N = 512, K = 512. B^T layout (w_ih rows are k-contiguous).
// 128x128 block tile, 4 waves 2x2, 64x64/wave via 4x4 frags of 16x16x32.
// Staging via global_load_lds (16B) into XOR-swizzled LDS. (unchanged)
// ---------------------------------------------------------------------------
#define GBK 64

__global__ __launch_bounds__(256) void gemm_bt(const unsigned short* __restrict__ A,
                                               const unsigned short* __restrict__ Bw,
                                               const float* __restrict__ bias,
                                               float* __restrict__ C) {
  __shared__ __align__(16) unsigned short As[128 * 64];
  __shared__ __align__(16) unsigned short Bs[128 * 64];
  const int K = 512, NO = 512;
  int tid = threadIdx.x;
  int lane = tid & 63;
  int wave = tid >> 6;
  int wm = wave & 1, wn = wave >> 1;
  int l15 = lane & 15;
  int quad = lane >> 4;
  int mtile = blockIdx.x, ntile = blockIdx.y;

  floatx4 acc[4][4];
#pragma unroll
  for (int i = 0; i < 4; ++i)
#pragma unroll
    for (int j = 0; j < 4; ++j) acc[i][j] = (floatx4){0.f, 0.f, 0.f, 0.f};

  // staging addresses
  int lr = lane >> 3;                 // local row within wave-slot (0..7)
  int lc = (lane & 7) ^ lr;           // swizzled global k-chunk for this lane
  const size_t lane_goff = (size_t)lr * K + lc * 8;
  const size_t abase = (size_t)mtile * 128 * K + lane_goff;
  const size_t bbase = (size_t)ntile * 128 * K + lane_goff;
  // MFMA read swizzle (lane-static)
  int sw = (quad ^ (l15 & 7)) * 8;    // element offset of chunk for kh=0

  for (int kb = 0; kb < K; kb += GBK) {
#pragma unroll
    for (int slot = 0; slot < 4; ++slot) {
      int r0 = slot * 32 + wave * 8;
      async_load16(A + abase + (size_t)r0 * K + kb, &As[r0 * 64]);
      async_load16(Bw + bbase + (size_t)r0 * K + kb, &Bs[r0 * 64]);
    }
    __syncthreads();   // drains vmcnt(0): LDS-DMA complete
#pragma unroll
    for (int kh = 0; kh < 2; ++kh) {
      int sc = sw ^ (kh * 32);        // ^ (4 chunks * 8 elem)
      short8 af[4], bf[4];
#pragma unroll
      for (int i = 0; i < 4; ++i)
        af[i] = *(const short8*)(&As[(wm * 64 + i * 16 + l15) * 64 + sc]);
#pragma unroll
      for (int j = 0; j < 4; ++j)
        bf[j] = *(const short8*)(&Bs[(wn * 64 + j * 16 + l15) * 64 + sc]);
#pragma unroll
      for (int i = 0; i < 4; ++i)
#pragma unroll
        for (int j = 0; j < 4; ++j)
          acc[i][j] = __builtin_amdgcn_mfma_f32_16x16x32_bf16(af[i], bf[j], acc[i][j], 0, 0, 0);
    }
    __syncthreads();
  }

  // Epilogue: C/D mapping col = lane&15 (n), row = quad*4 + reg (m)
  int m0 = mtile * 128 + wm * 64;
  int n0 = ntile * 128 + wn * 64;
#pragma unroll
  for (int j = 0; j < 4; ++j) {
    int col = n0 + j * 16 + l15;
    float bsum = bias[col];
#pragma unroll
    for (int i = 0; i < 4; ++i) {
      int row = m0 + i * 16 + quad * 4;
#pragma unroll
      for (int r = 0; r < 4; ++r)
        C[(size_t)(row + r) * NO + col] = acc[i][j][r] + bsum;
    }
  }
}

// ---------------------------------------------------------------------------
// Kernel 5: sequential LSTM — 16-batch-per-block batched MFMA.
// R1/R2/R4/R5 post-mortems: four VALU structures all stuck at 1600-2600
// cyc/step; the invariant cost is the per-step serial fixed overhead
// (barrier + LDS round-trip + dep-chain latency at low waves/SIMD),
// amortized over ONE batch per block. Fix: amortize over 16 batches.
//
// 16 blocks (B/16), 512 thr / 8 waves. Per step: gates[16b x 512] =
// h[16b x 128] @ w_hh^T + G, via MFMA 16x16x32 (M = 16 real batches,
// zero replication — unlike the pre-session replicated-A version).
//  - wave wn owns units [wn*16, wn*16+16); col-frag j = gate j at cols
//    j*128 + wn*16 + l15  ->  each lane ends with i,f,g,o of ONE unit
//    for 4 batches (C/D rows quad*4+r). No cross-lane gate exchange.
//  - B-frags: 64 persistent VGPRs, loaded with the exact pattern the
//    verified pre-session kernel used (w_hh[(j*128+wn*16+l15)*128 + ...]).
//  - A-frags: h bf16 in LDS [2][16][128], XOR-swizzled
//    (byte ^= (row&7)<<4) to kill the 16-way row-bank conflict; 4
//    ds_read_b128/lane/step. h write-back: 4 ds_write_b16/lane.
//  - acc seeds from G via MFMA C-in: 16 scalar loads/lane, prefetched
//    2 steps ahead (in flight across the lgkmcnt-only barrier).
//  - activations: 40 trans-ops/lane over 4 batches; c[4] in VGPRs.
// Per-step/SIMD: MFMA ~620 (16x16x32 @ ~19.4 cyc/SIMD x 32), trans ~320,
// DS ~550/CU, overlapped -> ~800-900 cyc/step vs 1600+ for 1 batch.
// ---------------------------------------------------------------------------
__global__ __launch_bounds__(512, 1) void lstm_kernel(const float* __restrict__ G,
                                                      const float* __restrict__ w_hh,
                                                      float* __restrict__ Xe) {
  int b0 = blockIdx.x * 16;
  int tid = threadIdx.x;
  int wn = tid >> 6;         // wave 0..7 -> units [wn*16, wn*16+16)
  int lane = tid & 63;
  int l15 = lane & 15;
  int quad = lane >> 4;

  // Persistent B-frags: bfr[j][kf], gate j, k-frag kf (k = kf*32 + quad*8 + i)
  short8 bfr[4][4];
#pragma unroll
  for (int j = 0; j < 4; ++j) {
    const float* src = w_hh + (size_t)(j * 128 + wn * 16 + l15) * 128;
#pragma unroll
    for (int kf = 0; kf < 4; ++kf) {
      int k0 = kf * 32 + quad * 8;
      float4 lo = *(const float4*)(src + k0);
      float4 hi = *(const float4*)(src + k0 + 4);
      short8 v;
      v[0] = (short)f2bf(lo.x); v[1] = (short)f2bf(lo.y);
      v[2] = (short)f2bf(lo.z); v[3] = (short)f2bf(lo.w);
      v[4] = (short)f2bf(hi.x); v[5] = (short)f2bf(hi.y);
      v[6] = (short)f2bf(hi.z); v[7] = (short)f2bf(hi.w);
      bfr[j][kf] = v;
    }
  }

  // h LDS: [2][16 rows][128 units] bf16, byte-swizzled: byte ^= (row&7)<<4.
  __shared__ __align__(16) unsigned short h2[2][16 * 128];   // 2 x 4 KB
  {
    uint4 z;
    z.x = 0u; z.y = 0u; z.z = 0u; z.w = 0u;
    ((uint4*)h2)[tid] = z;                                   // h0 = 0 (both bufs)
  }
  __syncthreads();

  // G row bases for this lane's 4 batch rows (quad*4 + r).
  const float* Gr[4];
#pragma unroll
  for (int r = 0; r < 4; ++r)
    Gr[r] = G + ((size_t)(b0 + quad * 4 + r) * Tt) * 512 + wn * 16 + l15;

  float gcur[4][4], gnext[4][4];   // [j][r]
#pragma unroll
  for (int j = 0; j < 4; ++j)
#pragma unroll
    for (int r = 0; r < 4; ++r) {
      gcur[j][r] = Gr[r][0 * 512 + j * 128];
      gnext[j][r] = Gr[r][1 * 512 + j * 128];
    }

  float c0[4] = {0.f, 0.f, 0.f, 0.f};
  float* Xeb = Xe + (size_t)wn * 16 + l15;
  int swz = (l15 & 7) << 4;        // A-read swizzle for this lane's row

  for (int t = 0; t < Tt; ++t) {
    int cur = t & 1;
    // A-frags: row l15, bytes [kf*64 + quad*16) ^ swz of buf[cur]
    const char* hbase = (const char*)&h2[cur][0] + l15 * 256;
    short8 af[4];
#pragma unroll
    for (int kf = 0; kf < 4; ++kf)
      af[kf] = *(const short8*)(hbase + ((kf * 64 + quad * 16) ^ swz));

    // acc seeds = G (C-in of MFMA); rotate prefetch, issue t+2 loads early
    floatx4 acc[4];
#pragma unroll
    for (int j = 0; j < 4; ++j)
      acc[j] = (floatx4){gcur[j][0], gcur[j][1], gcur[j][2], gcur[j][3]};
#pragma unroll
    for (int j = 0; j < 4; ++j)
#pragma unroll
      for (int r = 0; r < 4; ++r) gcur[j][r] = gnext[j][r];
    if (t + 2 < Tt) {
#pragma unroll
      for (int r = 0; r < 4; ++r)
#pragma unroll
        for (int j = 0; j < 4; ++j)
          gnext[j][r] = Gr[r][(size_t)(t + 2) * 512 + j * 128];
    }

    // 16 MFMA: 4 gates x 4 k-frags (4 independent depth-4 chains)
#pragma unroll
    for (int kf = 0; kf < 4; ++kf)
#pragma unroll
      for (int j = 0; j < 4; ++j)
        acc[j] = __builtin_amdgcn_mfma_f32_16x16x32_bf16(af[kf], bfr[j][kf], acc[j], 0, 0, 0);

    // Nonlinearity: lane owns unit wn*16+l15, batches quad*4+r.
    unsigned short* hw = &h2[cur ^ 1][0];
#pragma unroll
    for (int r = 0; r < 4; ++r) {
      float si = sigmoid_fast(acc[0][r]);
      float sf = sigmoid_fast(acc[1][r]);
      float tg = tanh_fast(acc[2][r]);
      float so = sigmoid_fast(acc[3][r]);
      c0[r] = fmaf(sf, c0[r], si * tg);
      float hv = so * tanh_fast(c0[r]);
      int row = quad * 4 + r;
      int cb = (2 * (wn * 16 + l15)) ^ ((row & 7) << 4);
      *(unsigned short*)((char*)hw + row * 256 + cb) = f2bf(hv);
      Xeb[((size_t)(b0 + row) * Tt + t) * Hh] = hv;     // fire-and-forget
    }
    lds_barrier();   // LDS-only drain; G loads / Xe stores stay in flight
  }
}

// ---------------------------------------------------------------------------
extern "C" void kernel_launch(void* const* d_in, const int* in_sizes, int n_in,
                              void* d_out, int out_size, void* d_ws, size_t ws_size,
                              hipStream_t stream) {
  const float* X      = (const float*)d_in[0];
  const float* attn_w = (const float*)d_in[1];
  // d_in[2] = attn_b: cancels in softmax, unused
  const float* w_ih   = (const float*)d_in[3];
  const float* w_hh   = (const float*)d_in[4];
  const float* b_ih   = (const float*)d_in[5];
  const float* b_hh   = (const float*)d_in[6];

  float* Xt = (float*)d_out;                                  // (B,T,N)
  float* Xe = (float*)d_out + (size_t)Bb * Tt * Nn;           // (B,T,H)

  char* ws = (char*)d_ws;
  float*          bias  = (float*)(ws + 524288);               //     2 KB
  unsigned short* wb    = (unsigned short*)(ws + 526336);      //   512 KB
  unsigned short* xtb   = (unsigned short*)(ws + 1050624);     //    32 MB
  float*          G     = (float*)(ws + 34605056);             //    64 MB
  // total ws use ~97 MB

  prep_kernel<<<dim3(1024), dim3(256), 0, stream>>>(w_ih, b_ih, b_hh, wb, bias);
  alpha_scale_kernel<<<dim3(Bb), dim3(512), 0, stream>>>(X, attn_w, Xt, xtb);
  gemm_bt<<<dim3(256, 4), dim3(256), 0, stream>>>(xtb, wb, bias, G);
  lstm_kernel<<<dim3(Bb / 16), dim3(512), 0, stream>>>(G, w_hh, Xe);
}

// Round 8
// 271.973 us; speedup vs baseline: 1.3976x; 1.3976x over previous
//
#include <hip/hip_runtime.h>
#include <hip/hip_bf16.h>

// Problem constants
#define Bb 256
#define Tt 128
#define Nn 512
#define Hh 128
// 4H = 512

typedef __attribute__((ext_vector_type(4))) float floatx4;
typedef __attribute__((ext_vector_type(8))) short short8;
typedef _Float16 h2v_t __attribute__((ext_vector_type(2)));

__device__ __forceinline__ unsigned short f2bf(float f) {
  unsigned u = __float_as_uint(f);
  u += 0x7fffu + ((u >> 16) & 1u);   // round-to-nearest-even
  return (unsigned short)(u >> 16);
}

// Fast activations: v_exp + v_rcp (~1ulp each) instead of IEEE div sequences.
__device__ __forceinline__ float sigmoid_fast(float x) {
  return __builtin_amdgcn_rcpf(1.f + __expf(-x));
}
__device__ __forceinline__ float tanh_fast(float x) {
  float e = __expf(2.f * x);                       // inf-safe
  return 1.f - 2.f * __builtin_amdgcn_rcpf(e + 1.f);
}

// Workgroup barrier that does NOT drain vmcnt: only LDS ops are waited.
// Global loads/stores issued before it stay in flight across the barrier.
__device__ __forceinline__ void lds_barrier() {
  asm volatile("s_waitcnt lgkmcnt(0)" ::: "memory");
  __builtin_amdgcn_s_barrier();
  asm volatile("" ::: "memory");
}

__device__ __forceinline__ void async_load16(const void* g, void* lds) {
  __builtin_amdgcn_global_load_lds(
      (const __attribute__((address_space(1))) unsigned int*)g,
      (__attribute__((address_space(3))) unsigned int*)lds, 16, 0, 0);
}

// 2-MAC-per-lane fp16 dot with fp32 accumulate (v_dot2_f32_f16).
#if __has_builtin(__builtin_amdgcn_fdot2)
#define FDOT2(a, b, c) __builtin_amdgcn_fdot2((a), (b), (c), false)
#else
__device__ __forceinline__ float fdot2_sw(h2v_t a, h2v_t b, float c) {
  return fmaf((float)a.x, (float)b.x, fmaf((float)a.y, (float)b.y, (c)));
}
#define FDOT2(a, b, c) fdot2_sw((a), (b), (c))
#endif

// Quad-permute via DPP (VALU-speed cross-lane within groups of 4 lanes).
// 0xB1 = quad_perm [1,0,3,2] (xor 1); 0x4E = quad_perm [2,3,0,1] (xor 2).
template <int CTRL>
__device__ __forceinline__ float qperm(float x) {
#if __has_builtin(__builtin_amdgcn_update_dpp)
  return __uint_as_float((unsigned)__builtin_amdgcn_update_dpp(
      0, (int)__float_as_uint(x), CTRL, 0xf, 0xf, true));
#else
  return __shfl_xor(x, CTRL == 0xB1 ? 1 : 2, 64);
#endif
}

// ---------------------------------------------------------------------------
// Kernel 1: convert w_ih to bf16, precompute bias = b_ih + b_hh
// ---------------------------------------------------------------------------
__global__ void prep_kernel(const float* __restrict__ w_ih,
                            const float* __restrict__ b_ih,
                            const float* __restrict__ b_hh,
                            unsigned short* __restrict__ wb,
                            float* __restrict__ bias) {
  int i = blockIdx.x * 256 + threadIdx.x;
  if (i < 4 * Hh * Nn) wb[i] = f2bf(w_ih[i]);
  if (i < 4 * Hh) bias[i] = b_ih[i] + b_hh[i];
}

// ---------------------------------------------------------------------------
// Kernel 2: alpha[b,n] = softmax_n( sum_t X[b,t,n] * w_x[t] )
// (softmax shift-invariance kills the h/c-dependent scalar term)
// Coalesced: thread (c, tp) reads float4 column 4c for t in [32tp, 32tp+32)
// -> a wave's load is 64 consecutive float4 = 1 KB.  (R4-verified)
// ---------------------------------------------------------------------------
__global__ __launch_bounds__(512) void alpha_kernel(const float* __restrict__ X,
                                                    const float* __restrict__ attn_w,
                                                    float* __restrict__ alpha) {
  int b = blockIdx.x;
  int tid = threadIdx.x;
  int c = tid & 127;        // float4 column index (n = 4c..4c+3)
  int tp = tid >> 7;        // 4-way t-split
  const float4* Xb = (const float4*)(X + (size_t)b * Tt * Nn) + c;
  const float* wx = attn_w + 2 * Hh;

  float4 acc = {0.f, 0.f, 0.f, 0.f};
#pragma unroll 8
  for (int tt = 0; tt < 32; ++tt) {
    int t = tp * 32 + tt;
    float4 x = Xb[(size_t)t * 128];
    float w = wx[t];
    acc.x = fmaf(x.x, w, acc.x);
    acc.y = fmaf(x.y, w, acc.y);
    acc.z = fmaf(x.z, w, acc.z);
    acc.w = fmaf(x.w, w, acc.w);
  }

  __shared__ float4 s4[512];     // 8 KB
  __shared__ float sred[128];
  s4[tid] = acc;
  __syncthreads();

  float4 sc = {0.f, 0.f, 0.f, 0.f};
  if (tid < 128) {
    float4 a = s4[tid], b2 = s4[tid + 128], c2 = s4[tid + 256], d = s4[tid + 384];
    sc.x = a.x + b2.x + c2.x + d.x;
    sc.y = a.y + b2.y + c2.y + d.y;
    sc.z = a.z + b2.z + c2.z + d.z;
    sc.w = a.w + b2.w + c2.w + d.w;
    sred[tid] = fmaxf(fmaxf(sc.x, sc.y), fmaxf(sc.z, sc.w));
  }
  __syncthreads();
  for (int s = 64; s > 0; s >>= 1) {
    if (tid < s) sred[tid] = fmaxf(sred[tid], sred[tid + s]);
    __syncthreads();
  }
  float m = sred[0];
  __syncthreads();

  float4 e4 = {0.f, 0.f, 0.f, 0.f};
  if (tid < 128) {
    e4.x = __expf(sc.x - m);
    e4.y = __expf(sc.y - m);
    e4.z = __expf(sc.z - m);
    e4.w = __expf(sc.w - m);
    sred[tid] = e4.x + e4.y + e4.z + e4.w;
  }
  __syncthreads();
  for (int s = 64; s > 0; s >>= 1) {
    if (tid < s) sred[tid] += sred[tid + s];
    __syncthreads();
  }
  float inv = 1.f / sred[0];     // one precise division per block
  if (tid < 128) {
    float4 out;
    out.x = e4.x * inv; out.y = e4.y * inv; out.z = e4.z * inv; out.w = e4.w * inv;
    ((float4*)(alpha + (size_t)b * Nn))[tid] = out;
  }
}

// ---------------------------------------------------------------------------
// Kernel 3: Xt = alpha * X (fp32, output 0) and xtb = bf16(Xt) for the GEMM
// ---------------------------------------------------------------------------
__global__ __launch_bounds__(256) void scale_kernel(const float* __restrict__ X,
                                                    const float* __restrict__ alpha,
                                                    float* __restrict__ Xt,
                                                    unsigned short* __restrict__ xtb) {
  size_t i = (size_t)blockIdx.x * 256 + threadIdx.x;  // float4 index; grid is exact
  size_t e = i * 4;
  int n = (int)(e & (Nn - 1));
  int brow = (int)(e >> 9);   // b*T + t
  int b = brow >> 7;          // T = 128
  float4 x = ((const float4*)X)[i];
  float4 a = *(const float4*)(alpha + (size_t)b * Nn + n);
  float4 y;
  y.x = x.x * a.x; y.y = x.y * a.y; y.z = x.z * a.z; y.w = x.w * a.w;
  ((float4*)Xt)[i] = y;
  ushort4 u;
  u.x = f2bf(y.x); u.y = f2bf(y.y); u.z = f2bf(y.z); u.w = f2bf(y.w);
  ((ushort4*)xtb)[i] = u;
}

// ---------------------------------------------------------------------------
// Kernel 4: G[m, j] = sum_k xtb[m,k] * w_ih[j,k] + bias[j]   (bf16 MFMA)
// M = B*T = 32768, N = 512, K = 512. B^T layout (w_ih rows are k-contiguous).
// 128x128 block tile, 4 waves 2x2, 64x64/wave via 4x4 frags of 16x16x32.
// Staging via global_load_lds (16B) into XOR-swizzled LDS. (verified)
// ---------------------------------------------------------------------------
#define GBK 64

__global__ __launch_bounds__(256) void gemm_bt(const unsigned short* __restrict__ A,
                                               const unsigned short* __restrict__ Bw,
                                               const float* __restrict__ bias,
                                               float* __restrict__ C) {
  __shared__ __align__(16) unsigned short As[128 * 64];
  __shared__ __align__(16) unsigned short Bs[128 * 64];
  const int K = 512, NO = 512;
  int tid = threadIdx.x;
  int lane = tid & 63;
  int wave = tid >> 6;
  int wm = wave & 1, wn = wave >> 1;
  int l15 = lane & 15;
  int quad = lane >> 4;
  int mtile = blockIdx.x, ntile = blockIdx.y;

  floatx4 acc[4][4];
#pragma unroll
  for (int i = 0; i < 4; ++i)
#pragma unroll
    for (int j = 0; j < 4; ++j) acc[i][j] = (floatx4){0.f, 0.f, 0.f, 0.f};

  // staging addresses
  int lr = lane >> 3;                 // local row within wave-slot (0..7)
  int lc = (lane & 7) ^ lr;           // swizzled global k-chunk for this lane
  const size_t lane_goff = (size_t)lr * K + lc * 8;
  const size_t abase = (size_t)mtile * 128 * K + lane_goff;
  const size_t bbase = (size_t)ntile * 128 * K + lane_goff;
  // MFMA read swizzle (lane-static)
  int sw = (quad ^ (l15 & 7)) * 8;    // element offset of chunk for kh=0

  for (int kb = 0; kb < K; kb += GBK) {
#pragma unroll
    for (int slot = 0; slot < 4; ++slot) {
      int r0 = slot * 32 + wave * 8;
      async_load16(A + abase + (size_t)r0 * K + kb, &As[r0 * 64]);
      async_load16(Bw + bbase + (size_t)r0 * K + kb, &Bs[r0 * 64]);
    }
    __syncthreads();   // drains vmcnt(0): LDS-DMA complete
#pragma unroll
    for (int kh = 0; kh < 2; ++kh) {
      int sc = sw ^ (kh * 32);        // ^ (4 chunks * 8 elem)
      short8 af[4], bf[4];
#pragma unroll
      for (int i = 0; i < 4; ++i)
        af[i] = *(const short8*)(&As[(wm * 64 + i * 16 + l15) * 64 + sc]);
#pragma unroll
      for (int j = 0; j < 4; ++j)
        bf[j] = *(const short8*)(&Bs[(wn * 64 + j * 16 + l15) * 64 + sc]);
#pragma unroll
      for (int i = 0; i < 4; ++i)
#pragma unroll
        for (int j = 0; j < 4; ++j)
          acc[i][j] = __builtin_amdgcn_mfma_f32_16x16x32_bf16(af[i], bf[j], acc[i][j], 0, 0, 0);
    }
    __syncthreads();
  }

  // Epilogue: C/D mapping col = lane&15 (n), row = quad*4 + reg (m)
  int m0 = mtile * 128 + wm * 64;
  int n0 = ntile * 128 + wn * 64;
#pragma unroll
  for (int j = 0; j < 4; ++j) {
    int col = n0 + j * 16 + l15;
    float bsum = bias[col];
#pragma unroll
    for (int i = 0; i < 4; ++i) {
      int row = m0 + i * 16 + quad * 4;
#pragma unroll
      for (int r = 0; r < 4; ++r)
        C[(size_t)(row + r) * NO + col] = acc[i][j][r] + bsum;
    }
  }
}

// ---------------------------------------------------------------------------
// Kernel 5: sequential LSTM — R1's 4-way k-split VALU dot2 recurrence,
// the fastest measured variant of this session (85.5 µs, R1 bench).
// Thread j = 4u+q owns unit u (0..127), k-quarter q (0..3):
//  - persistent VGPR weights: w_hh[f*128+u][32q..32q+32) fp16-packed, 64 regs
//  - h fp16 in LDS (2x256 B dbuf); 4 broadcast ds_read_b128/lane/step
//  - 4-lane quad DPP butterfly reduce (xor1, xor2); G bias folds in
//    pre-reduction (lane q seeds gate-q partial with G[q*128+u])
//  - all lanes compute the (identical) nonlinearity; q==0 commits h + Xe
//  - single lgkmcnt-only barrier/step; G prefetched 2 steps ahead
// Session record: 5 alternative structures (gate-split, ring-systolic,
// 8-way window, 16-batch MFMA) all measured SLOWER — the ~1600 cyc/step
// is the 1-batch-per-CU barrier+latency critical path; do not re-derive.
// ---------------------------------------------------------------------------
__global__ __launch_bounds__(512, 1) void lstm_kernel(const float* __restrict__ G,
                                                      const float* __restrict__ w_hh,
                                                      float* __restrict__ Xe) {
  int b = blockIdx.x;
  int tid = threadIdx.x;
  int u = tid >> 2;      // unit 0..127
  int q = tid & 3;       // k-quarter / gate-bias slot

  // Preload this lane's w_hh slice: rows f*128+u, cols [32q, 32q+32), fp16.
  h2v_t wreg[4][16];
#pragma unroll
  for (int f = 0; f < 4; ++f) {
    const float4* wr = (const float4*)(w_hh + ((size_t)(f * 128 + u) * 128 + q * 32));
#pragma unroll
    for (int i = 0; i < 8; ++i) {
      float4 v = wr[i];
      wreg[f][2 * i]     = (h2v_t){(_Float16)v.x, (_Float16)v.y};
      wreg[f][2 * i + 1] = (h2v_t){(_Float16)v.z, (_Float16)v.w};
    }
  }

  __shared__ __align__(16) unsigned short h2[2][128];   // fp16 h, double-buffered
  if (tid < 128) h2[0][tid] = 0;
  __syncthreads();

  const float* Gb = G + (size_t)b * Tt * 512 + q * 128 + u;
  float* Xeb = Xe + (size_t)b * Tt * Hh;

  float gcur = Gb[0];
  float gnext = Gb[512];
  float c0 = 0.f;

#define H2F(W) __builtin_bit_cast(h2v_t, (W))

  for (int t = 0; t < Tt; ++t) {
    int cur = t & 1;
    // Broadcast-read this lane's h quarter: bytes [64q, 64q+64) of buf[cur].
    const uint4* hp = (const uint4*)(&h2[cur][0]) + q * 4;
    uint4 ha = hp[0], hb = hp[1], hc = hp[2], hd = hp[3];

    float g_this = gcur;
    gcur = gnext;
    if (t + 2 < Tt) gnext = Gb[(size_t)(t + 2) * 512];   // in flight across barrier

    float pg0 = (q == 0) ? g_this : 0.f;
    float pg1 = (q == 1) ? g_this : 0.f;
    float pg2 = (q == 2) ? g_this : 0.f;
    float pg3 = (q == 3) ? g_this : 0.f;

#define DOTK(HB, K2)                                                \
  {                                                                 \
    h2v_t hh = __builtin_bit_cast(h2v_t, (HB));                     \
    pg0 = FDOT2(hh, wreg[0][K2], pg0);                              \
    pg1 = FDOT2(hh, wreg[1][K2], pg1);                              \
    pg2 = FDOT2(hh, wreg[2][K2], pg2);                              \
    pg3 = FDOT2(hh, wreg[3][K2], pg3);                              \
  }
    DOTK(ha.x, 0)  DOTK(ha.y, 1)  DOTK(ha.z, 2)  DOTK(ha.w, 3)
    DOTK(hb.x, 4)  DOTK(hb.y, 5)  DOTK(hb.z, 6)  DOTK(hb.w, 7)
    DOTK(hc.x, 8)  DOTK(hc.y, 9)  DOTK(hc.z, 10) DOTK(hc.w, 11)
    DOTK(hd.x, 12) DOTK(hd.y, 13) DOTK(hd.z, 14) DOTK(hd.w, 15)
#undef DOTK

    // Sum k-quarters across the 4 lanes of this quad (DPP butterfly).
    pg0 += qperm<0xB1>(pg0); pg1 += qperm<0xB1>(pg1);
    pg2 += qperm<0xB1>(pg2); pg3 += qperm<0xB1>(pg3);
    pg0 += qperm<0x4E>(pg0); pg1 += qperm<0x4E>(pg1);
    pg2 += qperm<0x4E>(pg2); pg3 += qperm<0x4E>(pg3);

    float si = sigmoid_fast(pg0);
    float sf = sigmoid_fast(pg1);
    float tg = tanh_fast(pg2);
    float so = sigmoid_fast(pg3);
    c0 = sf * c0 + si * tg;
    float hv = so * tanh_fast(c0);

    if (q == 0) {
      Xeb[(size_t)t * Hh + u] = hv;                       // fire-and-forget
      h2[cur ^ 1][u] = __builtin_bit_cast(unsigned short, (_Float16)hv);
    }
    lds_barrier();   // LDS-only drain; G loads / Xe stores stay in flight
  }
#undef H2F
}

// ---------------------------------------------------------------------------
extern "C" void kernel_launch(void* const* d_in, const int* in_sizes, int n_in,
                              void* d_out, int out_size, void* d_ws, size_t ws_size,
                              hipStream_t stream) {
  const float* X      = (const float*)d_in[0];
  const float* attn_w = (const float*)d_in[1];
  // d_in[2] = attn_b: cancels in softmax, unused
  const float* w_ih   = (const float*)d_in[3];
  const float* w_hh   = (const float*)d_in[4];
  const float* b_ih   = (const float*)d_in[5];
  const float* b_hh   = (const float*)d_in[6];

  float* Xt = (float*)d_out;                                  // (B,T,N)
  float* Xe = (float*)d_out + (size_t)Bb * Tt * Nn;           // (B,T,H)

  char* ws = (char*)d_ws;
  float*          alpha = (float*)(ws);                        //   512 KB
  float*          bias  = (float*)(ws + 524288);               //     2 KB
  unsigned short* wb    = (unsigned short*)(ws + 526336);      //   512 KB
  unsigned short* xtb   = (unsigned short*)(ws + 1050624);     //    32 MB
  float*          G     = (float*)(ws + 34605056);             //    64 MB
  // total ws use ~97 MB

  prep_kernel<<<dim3(1024), dim3(256), 0, stream>>>(w_ih, b_ih, b_hh, wb, bias);
  alpha_kernel<<<dim3(Bb), dim3(512), 0, stream>>>(X, attn_w, alpha);
  scale_kernel<<<dim3(16384), dim3(256), 0, stream>>>(X, alpha, Xt, xtb);
  gemm_bt<<<dim3(256, 4), dim3(256), 0, stream>>>(xtb, wb, bias, G);
  lstm_kernel<<<dim3(Bb), dim3(512), 0, stream>>>(G, w_hh, Xe);
}